// Round 1
// baseline (2025.273 us; speedup 1.0000x reference)
//
#include <hip/hip_runtime.h>
#include <math.h>

#define D 256
#define HW 784
#define NB 128

// ---------------- mean over spatial ----------------
__global__ __launch_bounds__(256) void mean_kernel(const float* __restrict__ pro,
                                                   float* __restrict__ g) {
  int b = blockIdx.y;
  int c = blockIdx.x * 4 + (threadIdx.x >> 6);
  int lane = threadIdx.x & 63;
  const float* p = pro + ((size_t)b * D + c) * HW;
  float s = 0.f;
  for (int i = lane; i < HW; i += 64) s += p[i];
#pragma unroll
  for (int o = 32; o > 0; o >>= 1) s += __shfl_down(s, o);
  if (lane == 0) g[b * D + c] = s * (1.0f / (float)HW);
}

// ---------------- att MLP + s_att outer ----------------
__global__ __launch_bounds__(256) void att_kernel(const float* __restrict__ g,
                                                  const float* __restrict__ w1,
                                                  const float* __restrict__ w2,
                                                  float* __restrict__ att,
                                                  float* __restrict__ satt) {
  __shared__ float gs[D];
  __shared__ float hs[16];
  __shared__ float as[D];
  int b = blockIdx.x, t = threadIdx.x;
  gs[t] = g[b * D + t];
  __syncthreads();
  if (t < 16) {
    float s = 0.f;
    for (int c = 0; c < D; ++c) s = fmaf(w1[t * D + c], gs[c], s);
    hs[t] = s;
  }
  __syncthreads();
  float s = 0.f;
#pragma unroll
  for (int k = 0; k < 16; ++k) s = fmaf(w2[t * 16 + k], hs[k], s);
  float a = 1.0f / (1.0f + expf(-s));
  as[t] = a;
  att[b * D + t] = a;
  __syncthreads();
  float* sb = satt + (size_t)b * D * D;
  for (int e = t; e < D * D; e += 256) sb[e] = as[e >> 8] * as[e & 255];
}

// ---------------- covariance A = X@X^T/784 - g g^T ----------------
__global__ __launch_bounds__(256) void gram_kernel(const float* __restrict__ pro,
                                                   const float* __restrict__ g,
                                                   float* __restrict__ Aout) {
  int b = blockIdx.y;
  int bi = blockIdx.x & 1, bj = blockIdx.x >> 1;
  const float* Xb = pro + (size_t)b * D * HW;
  __shared__ __align__(16) float As[16][132];
  __shared__ __align__(16) float Bs[16][132];
  int t = threadIdx.x;
  int tx = t & 15, ty = t >> 4;
  int r0 = ty * 8, c0 = tx * 8;
  float acc[8][8] = {};
  for (int k0 = 0; k0 < HW; k0 += 16) {
#pragma unroll
    for (int l = 0; l < 2; ++l) {
      int li = t + l * 256;
      int row = li >> 2, kf = (li & 3) << 2;
      float4 v = *(const float4*)(Xb + (size_t)(bi * 128 + row) * HW + k0 + kf);
      As[kf + 0][row] = v.x; As[kf + 1][row] = v.y; As[kf + 2][row] = v.z; As[kf + 3][row] = v.w;
      float4 w = *(const float4*)(Xb + (size_t)(bj * 128 + row) * HW + k0 + kf);
      Bs[kf + 0][row] = w.x; Bs[kf + 1][row] = w.y; Bs[kf + 2][row] = w.z; Bs[kf + 3][row] = w.w;
    }
    __syncthreads();
#pragma unroll
    for (int k = 0; k < 16; ++k) {
      float a[8], bv[8];
      *(float4*)(a)     = *(const float4*)&As[k][r0];
      *(float4*)(a + 4) = *(const float4*)&As[k][r0 + 4];
      *(float4*)(bv)     = *(const float4*)&Bs[k][c0];
      *(float4*)(bv + 4) = *(const float4*)&Bs[k][c0 + 4];
#pragma unroll
      for (int i = 0; i < 8; ++i)
#pragma unroll
        for (int j = 0; j < 8; ++j) acc[i][j] = fmaf(a[i], bv[j], acc[i][j]);
    }
    __syncthreads();
  }
  const float inv = 1.0f / (float)HW;
  const float* gb = g + b * D;
  float* Cb = Aout + (size_t)b * D * D;
#pragma unroll
  for (int i = 0; i < 8; ++i) {
    int gi = bi * 128 + r0 + i;
    float gv = gb[gi];
    float vals[8];
#pragma unroll
    for (int j = 0; j < 8; ++j) {
      int gj = bj * 128 + c0 + j;
      vals[j] = fmaf(-gv, gb[gj], acc[i][j] * inv);
    }
    *(float4*)(Cb + (size_t)gi * D + bj * 128 + c0)     = *(float4*)(vals);
    *(float4*)(Cb + (size_t)gi * D + bj * 128 + c0 + 4) = *(float4*)(vals + 4);
  }
}

// ---------------- trace ----------------
__global__ void trace_kernel(const float* __restrict__ A, float* __restrict__ stats) {
  int b = blockIdx.x;
  int l = threadIdx.x; // 64 threads
  float s = 0.f;
  for (int d = l; d < D; d += 64) s += A[(size_t)b * D * D + d * (D + 1)];
#pragma unroll
  for (int o = 32; o > 0; o >>= 1) s += __shfl_down(s, o);
  if (l == 0) {
    stats[b] = 1.0f / s;        // invNorm
    stats[NB + b] = sqrtf(s);   // sqrtNorm
  }
}

// ---------------- init: Y0 = A/norm, ZY0 = 1.5I - 0.5 Y0, L=0 ----------------
__global__ __launch_bounds__(256) void init_kernel(const float* __restrict__ A,
                                                   const float* __restrict__ stats, int b0,
                                                   float* __restrict__ Y, float* __restrict__ ZY,
                                                   float* __restrict__ L1, float* __restrict__ L2) {
  int idx = blockIdx.x * 256 + threadIdx.x;   // one float4 per thread
  int bloc = idx >> 14;
  int m4 = idx & 16383;
  int i = m4 >> 6;
  int j0 = (m4 & 63) << 2;
  float invn = stats[b0 + bloc];
  float4 a = *(const float4*)(A + ((size_t)(b0 + bloc) << 16) + ((size_t)m4 << 2));
  float4 y, z;
  y.x = a.x * invn; y.y = a.y * invn; y.z = a.z * invn; y.w = a.w * invn;
  z.x = (i == j0 + 0 ? 1.5f : 0.f) - 0.5f * y.x;
  z.y = (i == j0 + 1 ? 1.5f : 0.f) - 0.5f * y.y;
  z.z = (i == j0 + 2 ? 1.5f : 0.f) - 0.5f * y.z;
  z.w = (i == j0 + 3 ? 1.5f : 0.f) - 0.5f * y.w;
  size_t o = (size_t)idx << 2;
  *(float4*)(Y + o) = y;
  *(float4*)(ZY + o) = z;
  float4 zr = make_float4(0.f, 0.f, 0.f, 0.f);
  *(float4*)(L1 + o) = zr;
  *(float4*)(L2 + o) = zr;
}

__device__ __forceinline__ float j1_of(float y, float l1, bool diag, float eta, float c1d) {
  float j1 = fmaf(-eta, l1, y);
  return diag ? j1 * c1d : j1;
}
__device__ __forceinline__ float j2_of(float y, float l2, float oma, float eta, float ebb) {
  return fmaf(-eta, l2, y) * (1.0f - ebb * oma);
}

// ---------------- pre: Ypre = 0.5(J1+J2) + eta3(L1+L2) ----------------
__global__ __launch_bounds__(256) void pre_kernel(const float* __restrict__ Y,
                                                  const float* __restrict__ L1,
                                                  const float* __restrict__ L2,
                                                  const float* __restrict__ att, int b0,
                                                  float* __restrict__ Yp,
                                                  float eta, float c1d, float ebb, float eta3) {
  int idx = blockIdx.x * 256 + threadIdx.x;
  int bloc = idx >> 14;
  int m4 = idx & 16383;
  int i = m4 >> 6;
  int j0 = (m4 & 63) << 2;
  size_t o = (size_t)idx << 2;
  float4 y = *(const float4*)(Y + o);
  float4 l1 = *(const float4*)(L1 + o);
  float4 l2 = *(const float4*)(L2 + o);
  float ai = att[(b0 + bloc) * D + i];
  float4 aj = *(const float4*)(att + (b0 + bloc) * D + j0);
  float4 r;
  {
    float j1 = j1_of(y.x, l1.x, i == j0 + 0, eta, c1d);
    float j2 = j2_of(y.x, l2.x, 1.0f - ai * aj.x, eta, ebb);
    r.x = 0.5f * (j1 + j2) + eta3 * (l1.x + l2.x);
  }
  {
    float j1 = j1_of(y.y, l1.y, i == j0 + 1, eta, c1d);
    float j2 = j2_of(y.y, l2.y, 1.0f - ai * aj.y, eta, ebb);
    r.y = 0.5f * (j1 + j2) + eta3 * (l1.y + l2.y);
  }
  {
    float j1 = j1_of(y.z, l1.z, i == j0 + 2, eta, c1d);
    float j2 = j2_of(y.z, l2.z, 1.0f - ai * aj.z, eta, ebb);
    r.z = 0.5f * (j1 + j2) + eta3 * (l1.z + l2.z);
  }
  {
    float j1 = j1_of(y.w, l1.w, i == j0 + 3, eta, c1d);
    float j2 = j2_of(y.w, l2.w, 1.0f - ai * aj.w, eta, ebb);
    r.w = 0.5f * (j1 + j2) + eta3 * (l1.w + l2.w);
  }
  *(float4*)(Yp + o) = r;
}

// ---------------- post: L updates ----------------
__global__ __launch_bounds__(256) void post_kernel(const float* __restrict__ Yold,
                                                   const float* __restrict__ Ynew,
                                                   float* __restrict__ L1, float* __restrict__ L2,
                                                   const float* __restrict__ att, int b0,
                                                   float mu, float eta, float c1d, float ebb) {
  int idx = blockIdx.x * 256 + threadIdx.x;
  int bloc = idx >> 14;
  int m4 = idx & 16383;
  int i = m4 >> 6;
  int j0 = (m4 & 63) << 2;
  size_t o = (size_t)idx << 2;
  float4 y = *(const float4*)(Yold + o);
  float4 yn = *(const float4*)(Ynew + o);
  float4 l1 = *(const float4*)(L1 + o);
  float4 l2 = *(const float4*)(L2 + o);
  float ai = att[(b0 + bloc) * D + i];
  float4 aj = *(const float4*)(att + (b0 + bloc) * D + j0);
  float4 n1, n2;
  {
    float j1 = j1_of(y.x, l1.x, i == j0 + 0, eta, c1d);
    float j2 = j2_of(y.x, l2.x, 1.0f - ai * aj.x, eta, ebb);
    n1.x = fmaf(0.9f, l1.x, mu * (j1 - yn.x));
    n2.x = fmaf(0.9f, l2.x, mu * (j2 - yn.x));
  }
  {
    float j1 = j1_of(y.y, l1.y, i == j0 + 1, eta, c1d);
    float j2 = j2_of(y.y, l2.y, 1.0f - ai * aj.y, eta, ebb);
    n1.y = fmaf(0.9f, l1.y, mu * (j1 - yn.y));
    n2.y = fmaf(0.9f, l2.y, mu * (j2 - yn.y));
  }
  {
    float j1 = j1_of(y.z, l1.z, i == j0 + 2, eta, c1d);
    float j2 = j2_of(y.z, l2.z, 1.0f - ai * aj.z, eta, ebb);
    n1.z = fmaf(0.9f, l1.z, mu * (j1 - yn.z));
    n2.z = fmaf(0.9f, l2.z, mu * (j2 - yn.z));
  }
  {
    float j1 = j1_of(y.w, l1.w, i == j0 + 3, eta, c1d);
    float j2 = j2_of(y.w, l2.w, 1.0f - ai * aj.w, eta, ebb);
    n1.w = fmaf(0.9f, l1.w, mu * (j1 - yn.w));
    n2.w = fmaf(0.9f, l2.w, mu * (j2 - yn.w));
  }
  *(float4*)(L1 + o) = n1;
  *(float4*)(L2 + o) = n2;
}

// ---------------- batched 256x256x256 fp32 GEMM: C = alpha*(A@B) + delta*I ----------------
__global__ __launch_bounds__(256) void bmm_kernel(const float* __restrict__ Am,
                                                  const float* __restrict__ Bm,
                                                  float* __restrict__ Cm,
                                                  float alpha, float delta) {
  int b = blockIdx.y;
  int bi = blockIdx.x & 1, bj = blockIdx.x >> 1;
  const float* Ab = Am + (size_t)b * D * D;
  const float* Bb = Bm + (size_t)b * D * D;
  float* Cb = Cm + (size_t)b * D * D;
  __shared__ __align__(16) float As[16][132];
  __shared__ __align__(16) float Bs[16][132];
  int t = threadIdx.x;
  int tx = t & 15, ty = t >> 4;
  int r0 = ty * 8, c0 = tx * 8;
  float acc[8][8] = {};
  for (int k0 = 0; k0 < D; k0 += 16) {
#pragma unroll
    for (int l = 0; l < 2; ++l) {
      int li = t + l * 256;
      int row = li >> 2, kf = (li & 3) << 2;
      float4 v = *(const float4*)(Ab + (size_t)(bi * 128 + row) * D + k0 + kf);
      As[kf + 0][row] = v.x; As[kf + 1][row] = v.y; As[kf + 2][row] = v.z; As[kf + 3][row] = v.w;
      int kr = li >> 5, cf = (li & 31) << 2;
      *(float4*)(&Bs[kr][cf]) = *(const float4*)(Bb + (size_t)(k0 + kr) * D + bj * 128 + cf);
    }
    __syncthreads();
#pragma unroll
    for (int k = 0; k < 16; ++k) {
      float a[8], bv[8];
      *(float4*)(a)     = *(const float4*)&As[k][r0];
      *(float4*)(a + 4) = *(const float4*)&As[k][r0 + 4];
      *(float4*)(bv)     = *(const float4*)&Bs[k][c0];
      *(float4*)(bv + 4) = *(const float4*)&Bs[k][c0 + 4];
#pragma unroll
      for (int i = 0; i < 8; ++i)
#pragma unroll
        for (int j = 0; j < 8; ++j) acc[i][j] = fmaf(a[i], bv[j], acc[i][j]);
    }
    __syncthreads();
  }
#pragma unroll
  for (int i = 0; i < 8; ++i) {
    int gi = bi * 128 + r0 + i;
    float vals[8];
#pragma unroll
    for (int j = 0; j < 8; ++j) {
      int gj = bj * 128 + c0 + j;
      vals[j] = alpha * acc[i][j] + ((gi == gj) ? delta : 0.f);
    }
    *(float4*)(Cb + (size_t)gi * D + bj * 128 + c0)     = *(float4*)(vals);
    *(float4*)(Cb + (size_t)gi * D + bj * 128 + c0 + 4) = *(float4*)(vals + 4);
  }
}

// ---------------- cls init with bias ----------------
__global__ __launch_bounds__(256) void cls_init_kernel(const float* __restrict__ fcb,
                                                       float* __restrict__ cls) {
  int e = blockIdx.x * 256 + threadIdx.x;  // 25600 exactly
  cls[e] = fcb[e % 200];
}

// ---------------- fc over tril-gathered Y ----------------
__global__ __launch_bounds__(256) void fc_kernel(const float* __restrict__ Yfin,
                                                 const float* __restrict__ fcw,
                                                 const float* __restrict__ stats,
                                                 float* __restrict__ cls,
                                                 int b0, int Bg) {
  const int KTOT = 32896;
  int bblk = blockIdx.x;
  int oblk = blockIdx.y;
  int kspl = blockIdx.z;
  int kbeg = kspl * 4112, kend = kbeg + 4112;
  __shared__ float fs[32][132];
  __shared__ float wsh[8][132];
  int t = threadIdx.x;
  int bb = t >> 3, oo = t & 7;
  float acc = 0.f;
  for (int k0 = kbeg; k0 < kend; k0 += 128) {
#pragma unroll
    for (int l = 0; l < 16; ++l) {
      int li = t + l * 256;
      int kk = li & 127, rb = li >> 7;
      int bl = bblk * 32 + rb;  // local batch
      int kg = k0 + kk;
      float v = 0.f;
      if (bl < Bg && kg < kend) {
        int i = (int)((sqrtf((float)(8 * kg + 1)) - 1.0f) * 0.5f);
        while ((i + 1) * (i + 2) / 2 <= kg) ++i;
        while (i * (i + 1) / 2 > kg) --i;
        int j = kg - i * (i + 1) / 2;
        v = Yfin[((size_t)bl << 16) + i * D + j];
      }
      fs[rb][kk] = v;
    }
#pragma unroll
    for (int l = 0; l < 4; ++l) {
      int li = t + l * 256;
      int kk = li & 127, ro = li >> 7;
      int kg = k0 + kk;
      wsh[ro][kk] = (kg < kend) ? fcw[(size_t)(oblk * 8 + ro) * KTOT + kg] : 0.f;
    }
    __syncthreads();
#pragma unroll 8
    for (int kk = 0; kk < 128; ++kk) acc = fmaf(fs[bb][kk], wsh[oo][kk], acc);
    __syncthreads();
  }
  int bl = bblk * 32 + bb;
  if (bl < Bg) {
    int bglob = b0 + bl;
    atomicAdd(&cls[bglob * 200 + oblk * 8 + oo], acc * stats[NB + bglob]);
  }
}

extern "C" void kernel_launch(void* const* d_in, const int* in_sizes, int n_in,
                              void* d_out, int out_size, void* d_ws, size_t ws_size,
                              hipStream_t stream) {
  const float* pro = (const float*)d_in[0];
  const float* w1  = (const float*)d_in[1];
  const float* w2  = (const float*)d_in[2];
  const float* fcw = (const float*)d_in[3];
  const float* fcb = (const float*)d_in[4];

  float* cls  = (float*)d_out;
  float* Aout = cls + 25600;
  float* satt = Aout + (size_t)NB * D * D;

  float* g     = (float*)d_ws;
  float* att   = g + NB * D;
  float* stats = att + NB * D;
  float* pool  = stats + 512;

  size_t fixedB = (size_t)(NB * D * 2 + 512) * sizeof(float);
  int Bg = NB;
  while (Bg > 1 && fixedB + 7ull * (size_t)Bg * D * D * sizeof(float) > ws_size) Bg >>= 1;

  mean_kernel<<<dim3(64, NB), 256, 0, stream>>>(pro, g);
  att_kernel<<<dim3(NB), 256, 0, stream>>>(g, w1, w2, att, satt);
  gram_kernel<<<dim3(4, NB), 256, 0, stream>>>(pro, g, Aout);
  trace_kernel<<<dim3(NB), 64, 0, stream>>>(Aout, stats);
  cls_init_kernel<<<dim3(100), 256, 0, stream>>>(fcb, cls);

  for (int b0 = 0; b0 < NB; b0 += Bg) {
    float* S[7];
    for (int i = 0; i < 7; ++i) S[i] = pool + (size_t)i * Bg * D * D;
    float *Y = S[0], *L1 = S[1], *L2 = S[2], *Z = S[3];
    float *f0 = S[4], *f1 = S[5], *f2 = S[6];
    int ge = Bg * 64;  // elementwise grid (Bg*16384 float4 / 256)

    init_kernel<<<dim3(ge), 256, 0, stream>>>(Aout, stats, b0, Y, Z, L1, L2);

    double mu = 0.5;
    for (int it = 0; it < 7; ++it) {
      float eta  = (float)(1.0 / mu);
      float c1d  = (float)(1.0 - 1e-3 / mu);
      float ebb  = (float)(1e-3 / mu);
      float eta3 = (float)(1.0 / (2.0 * mu));
      float muf  = (float)mu;

      pre_kernel<<<dim3(ge), 256, 0, stream>>>(Y, L1, L2, att, b0, f0, eta, c1d, ebb, eta3);

      float* ZYp;
      if (it == 0) {
        ZYp = Z;  // ZY0 computed in init
      } else {
        bmm_kernel<<<dim3(4, Bg), 256, 0, stream>>>(Z, f0, f1, -0.5f, 1.5f);  // ZY = 1.5I - 0.5 Z@Yp
        ZYp = f1;
      }
      bmm_kernel<<<dim3(4, Bg), 256, 0, stream>>>(f0, ZYp, f2, 1.0f, 0.f);    // Ynew = Yp@ZY

      if (it < 6) {
        float* Znew;
        if (it == 0) {
          Znew = Z;  // Z := ZY (already in place)
        } else {
          bmm_kernel<<<dim3(4, Bg), 256, 0, stream>>>(f1, Z, f0, 1.0f, 0.f);  // Znew = ZY@Z
          Znew = f0;
        }
        post_kernel<<<dim3(ge), 256, 0, stream>>>(Y, f2, L1, L2, att, b0, muf, eta, c1d, ebb);
        float* oldY = Y;
        float* oldZ = Z;
        Y = f2;
        if (it == 0) {
          f2 = oldY;            // free: oldY; f0,f1 still free
        } else {
          Z = Znew;             // = f0
          f0 = oldY;
          f2 = oldZ;            // f1 stays as scratch
        }
        mu *= 1.05;
      }
    }
    // final Y is in f2 (written by the last Ynew matmul at it==6)
    fc_kernel<<<dim3((Bg + 31) / 32, 25, 8), 256, 0, stream>>>(f2, fcw, stats, cls, b0, Bg);
  }
}

// Round 3
// 1911.716 us; speedup vs baseline: 1.0594x; 1.0594x over previous
//
#include <hip/hip_runtime.h>
#include <math.h>

#define D 256
#define HW 784
#define NB 128

// ---------------- mean over spatial ----------------
__global__ __launch_bounds__(256) void mean_kernel(const float* __restrict__ pro,
                                                   float* __restrict__ g) {
  int b = blockIdx.y;
  int c = blockIdx.x * 4 + (threadIdx.x >> 6);
  int lane = threadIdx.x & 63;
  const float* p = pro + ((size_t)b * D + c) * HW;
  float s = 0.f;
  for (int i = lane; i < HW; i += 64) s += p[i];
#pragma unroll
  for (int o = 32; o > 0; o >>= 1) s += __shfl_down(s, o);
  if (lane == 0) g[b * D + c] = s * (1.0f / (float)HW);
}

// ---------------- att MLP + s_att outer ----------------
__global__ __launch_bounds__(256) void att_kernel(const float* __restrict__ g,
                                                  const float* __restrict__ w1,
                                                  const float* __restrict__ w2,
                                                  float* __restrict__ att,
                                                  float* __restrict__ satt) {
  __shared__ float gs[D];
  __shared__ float hs[16];
  __shared__ float as[D];
  int b = blockIdx.x, t = threadIdx.x;
  gs[t] = g[b * D + t];
  __syncthreads();
  if (t < 16) {
    float s = 0.f;
    for (int c = 0; c < D; ++c) s = fmaf(w1[t * D + c], gs[c], s);
    hs[t] = s;
  }
  __syncthreads();
  float s = 0.f;
#pragma unroll
  for (int k = 0; k < 16; ++k) s = fmaf(w2[t * 16 + k], hs[k], s);
  float a = 1.0f / (1.0f + expf(-s));
  as[t] = a;
  att[b * D + t] = a;
  __syncthreads();
  float* sb = satt + (size_t)b * D * D;
  for (int e = t; e < D * D; e += 256) sb[e] = as[e >> 8] * as[e & 255];
}

// ---------------- covariance A = X@X^T/784 - g g^T ----------------
__global__ __launch_bounds__(256) void gram_kernel(const float* __restrict__ pro,
                                                   const float* __restrict__ g,
                                                   float* __restrict__ Aout) {
  int b = blockIdx.y;
  int bi = blockIdx.x & 1, bj = blockIdx.x >> 1;
  const float* Xb = pro + (size_t)b * D * HW;
  __shared__ __align__(16) float As[16][132];
  __shared__ __align__(16) float Bs[16][132];
  int t = threadIdx.x;
  int tx = t & 15, ty = t >> 4;
  int r0 = ty * 8, c0 = tx * 8;
  float acc[8][8] = {};
  for (int k0 = 0; k0 < HW; k0 += 16) {
#pragma unroll
    for (int l = 0; l < 2; ++l) {
      int li = t + l * 256;
      int row = li >> 2, kf = (li & 3) << 2;
      float4 v = *(const float4*)(Xb + (size_t)(bi * 128 + row) * HW + k0 + kf);
      As[kf + 0][row] = v.x; As[kf + 1][row] = v.y; As[kf + 2][row] = v.z; As[kf + 3][row] = v.w;
      float4 w = *(const float4*)(Xb + (size_t)(bj * 128 + row) * HW + k0 + kf);
      Bs[kf + 0][row] = w.x; Bs[kf + 1][row] = w.y; Bs[kf + 2][row] = w.z; Bs[kf + 3][row] = w.w;
    }
    __syncthreads();
#pragma unroll
    for (int k = 0; k < 16; ++k) {
      float a[8], bv[8];
      *(float4*)(a)     = *(const float4*)&As[k][r0];
      *(float4*)(a + 4) = *(const float4*)&As[k][r0 + 4];
      *(float4*)(bv)     = *(const float4*)&Bs[k][c0];
      *(float4*)(bv + 4) = *(const float4*)&Bs[k][c0 + 4];
#pragma unroll
      for (int i = 0; i < 8; ++i)
#pragma unroll
        for (int j = 0; j < 8; ++j) acc[i][j] = fmaf(a[i], bv[j], acc[i][j]);
    }
    __syncthreads();
  }
  const float inv = 1.0f / (float)HW;
  const float* gb = g + b * D;
  float* Cb = Aout + (size_t)b * D * D;
#pragma unroll
  for (int i = 0; i < 8; ++i) {
    int gi = bi * 128 + r0 + i;
    float gv = gb[gi];
    float vals[8];
#pragma unroll
    for (int j = 0; j < 8; ++j) {
      int gj = bj * 128 + c0 + j;
      vals[j] = fmaf(-gv, gb[gj], acc[i][j] * inv);
    }
    *(float4*)(Cb + (size_t)gi * D + bj * 128 + c0)     = *(float4*)(vals);
    *(float4*)(Cb + (size_t)gi * D + bj * 128 + c0 + 4) = *(float4*)(vals + 4);
  }
}

// ---------------- trace ----------------
__global__ void trace_kernel(const float* __restrict__ A, float* __restrict__ stats) {
  int b = blockIdx.x;
  int l = threadIdx.x; // 64 threads
  float s = 0.f;
  for (int d = l; d < D; d += 64) s += A[(size_t)b * D * D + d * (D + 1)];
#pragma unroll
  for (int o = 32; o > 0; o >>= 1) s += __shfl_down(s, o);
  if (l == 0) {
    stats[b] = 1.0f / s;        // invNorm
    stats[NB + b] = sqrtf(s);   // sqrtNorm
  }
}

// ---------------- init: Y0 = A/norm, ZY0 = 1.5I - 0.5 Y0, L=0 ----------------
__global__ __launch_bounds__(256) void init_kernel(const float* __restrict__ A,
                                                   const float* __restrict__ stats, int b0,
                                                   float* __restrict__ Y, float* __restrict__ ZY,
                                                   float* __restrict__ L1, float* __restrict__ L2) {
  int idx = blockIdx.x * 256 + threadIdx.x;   // one float4 per thread
  int bloc = idx >> 14;
  int m4 = idx & 16383;
  int i = m4 >> 6;
  int j0 = (m4 & 63) << 2;
  float invn = stats[b0 + bloc];
  float4 a = *(const float4*)(A + ((size_t)(b0 + bloc) << 16) + ((size_t)m4 << 2));
  float4 y, z;
  y.x = a.x * invn; y.y = a.y * invn; y.z = a.z * invn; y.w = a.w * invn;
  z.x = (i == j0 + 0 ? 1.5f : 0.f) - 0.5f * y.x;
  z.y = (i == j0 + 1 ? 1.5f : 0.f) - 0.5f * y.y;
  z.z = (i == j0 + 2 ? 1.5f : 0.f) - 0.5f * y.z;
  z.w = (i == j0 + 3 ? 1.5f : 0.f) - 0.5f * y.w;
  size_t o = (size_t)idx << 2;
  *(float4*)(Y + o) = y;
  *(float4*)(ZY + o) = z;
  float4 zr = make_float4(0.f, 0.f, 0.f, 0.f);
  *(float4*)(L1 + o) = zr;
  *(float4*)(L2 + o) = zr;
}

__device__ __forceinline__ float j1_of(float y, float l1, bool diag, float eta, float c1d) {
  float j1 = fmaf(-eta, l1, y);
  return diag ? j1 * c1d : j1;
}
__device__ __forceinline__ float j2_of(float y, float l2, float oma, float eta, float ebb) {
  return fmaf(-eta, l2, y) * (1.0f - ebb * oma);
}

// ---------------- pre: Ypre = 0.5(J1+J2) + eta3(L1+L2) ----------------
__global__ __launch_bounds__(256) void pre_kernel(const float* __restrict__ Y,
                                                  const float* __restrict__ L1,
                                                  const float* __restrict__ L2,
                                                  const float* __restrict__ att, int b0,
                                                  float* __restrict__ Yp,
                                                  float eta, float c1d, float ebb, float eta3) {
  int idx = blockIdx.x * 256 + threadIdx.x;
  int bloc = idx >> 14;
  int m4 = idx & 16383;
  int i = m4 >> 6;
  int j0 = (m4 & 63) << 2;
  size_t o = (size_t)idx << 2;
  float4 y = *(const float4*)(Y + o);
  float4 l1 = *(const float4*)(L1 + o);
  float4 l2 = *(const float4*)(L2 + o);
  float ai = att[(b0 + bloc) * D + i];
  float4 aj = *(const float4*)(att + (b0 + bloc) * D + j0);
  float4 r;
  {
    float j1 = j1_of(y.x, l1.x, i == j0 + 0, eta, c1d);
    float j2 = j2_of(y.x, l2.x, 1.0f - ai * aj.x, eta, ebb);
    r.x = 0.5f * (j1 + j2) + eta3 * (l1.x + l2.x);
  }
  {
    float j1 = j1_of(y.y, l1.y, i == j0 + 1, eta, c1d);
    float j2 = j2_of(y.y, l2.y, 1.0f - ai * aj.y, eta, ebb);
    r.y = 0.5f * (j1 + j2) + eta3 * (l1.y + l2.y);
  }
  {
    float j1 = j1_of(y.z, l1.z, i == j0 + 2, eta, c1d);
    float j2 = j2_of(y.z, l2.z, 1.0f - ai * aj.z, eta, ebb);
    r.z = 0.5f * (j1 + j2) + eta3 * (l1.z + l2.z);
  }
  {
    float j1 = j1_of(y.w, l1.w, i == j0 + 3, eta, c1d);
    float j2 = j2_of(y.w, l2.w, 1.0f - ai * aj.w, eta, ebb);
    r.w = 0.5f * (j1 + j2) + eta3 * (l1.w + l2.w);
  }
  *(float4*)(Yp + o) = r;
}

// ---------------- batched 256^3 fp32 GEMM, 64x64 tiles ----------------
// C = alpha*(A@B) + delta*I   (doPost=0)
// or Ynew = A@B with fused L-update epilogue, written over Yold (doPost=1)
__global__ __launch_bounds__(256) void bmm_kernel(const float* __restrict__ Am,
                                                  const float* __restrict__ Bm,
                                                  float* __restrict__ Cm,
                                                  const float* __restrict__ Yold,
                                                  float* __restrict__ L1,
                                                  float* __restrict__ L2,
                                                  const float* __restrict__ att, int b0,
                                                  float alpha, float delta,
                                                  int doPost, float mu, float eta,
                                                  float c1d, float ebb) {
  int b = blockIdx.y;
  int bi = blockIdx.x & 3, bj = blockIdx.x >> 2;
  const float* Ab = Am + ((size_t)b << 16);
  const float* Bb = Bm + ((size_t)b << 16);
  __shared__ __align__(16) float As[16][68];
  __shared__ __align__(16) float Bs[16][68];
  int t = threadIdx.x;
  int tx = t & 15, ty = t >> 4;
  int r0 = ty * 4, c0 = tx * 4;
  float acc[4][4] = {};
  for (int k0 = 0; k0 < D; k0 += 16) {
    {
      int row = t >> 2, kf = (t & 3) << 2;
      float4 v = *(const float4*)(Ab + (size_t)(bi * 64 + row) * D + k0 + kf);
      As[kf + 0][row] = v.x; As[kf + 1][row] = v.y; As[kf + 2][row] = v.z; As[kf + 3][row] = v.w;
      int kr = t >> 4, cf = (t & 15) << 2;
      *(float4*)(&Bs[kr][cf]) = *(const float4*)(Bb + (size_t)(k0 + kr) * D + bj * 64 + cf);
    }
    __syncthreads();
#pragma unroll
    for (int k = 0; k < 16; ++k) {
      float4 a = *(const float4*)&As[k][r0];
      float4 bv = *(const float4*)&Bs[k][c0];
      acc[0][0] = fmaf(a.x, bv.x, acc[0][0]);
      acc[0][1] = fmaf(a.x, bv.y, acc[0][1]);
      acc[0][2] = fmaf(a.x, bv.z, acc[0][2]);
      acc[0][3] = fmaf(a.x, bv.w, acc[0][3]);
      acc[1][0] = fmaf(a.y, bv.x, acc[1][0]);
      acc[1][1] = fmaf(a.y, bv.y, acc[1][1]);
      acc[1][2] = fmaf(a.y, bv.z, acc[1][2]);
      acc[1][3] = fmaf(a.y, bv.w, acc[1][3]);
      acc[2][0] = fmaf(a.z, bv.x, acc[2][0]);
      acc[2][1] = fmaf(a.z, bv.y, acc[2][1]);
      acc[2][2] = fmaf(a.z, bv.z, acc[2][2]);
      acc[2][3] = fmaf(a.z, bv.w, acc[2][3]);
      acc[3][0] = fmaf(a.w, bv.x, acc[3][0]);
      acc[3][1] = fmaf(a.w, bv.y, acc[3][1]);
      acc[3][2] = fmaf(a.w, bv.z, acc[3][2]);
      acc[3][3] = fmaf(a.w, bv.w, acc[3][3]);
    }
    __syncthreads();
  }
  float* Cb = Cm + ((size_t)b << 16);
  int gj0 = bj * 64 + c0;
  if (!doPost) {
#pragma unroll
    for (int i = 0; i < 4; ++i) {
      int gi = bi * 64 + r0 + i;
      float vals[4];
#pragma unroll
      for (int j = 0; j < 4; ++j)
        vals[j] = alpha * acc[i][j] + ((gi == gj0 + j) ? delta : 0.f);
      *(float4*)(Cb + (size_t)gi * D + gj0) = *(float4*)(vals);
    }
  } else {
    int bg = b0 + b;
    float4 aj = *(const float4*)(att + bg * D + gj0);
#pragma unroll
    for (int i = 0; i < 4; ++i) {
      int gi = bi * 64 + r0 + i;
      size_t ro = ((size_t)b << 16) + (size_t)gi * D + gj0;
      float ai = att[bg * D + gi];
      float4 y4 = *(const float4*)(Yold + ro);
      float4 l14 = *(const float4*)(L1 + ro);
      float4 l24 = *(const float4*)(L2 + ro);
      float yv[4] = {y4.x, y4.y, y4.z, y4.w};
      float l1v[4] = {l14.x, l14.y, l14.z, l14.w};
      float l2v[4] = {l24.x, l24.y, l24.z, l24.w};
      float av[4] = {aj.x, aj.y, aj.z, aj.w};
      float n1[4], n2[4], cv[4];
#pragma unroll
      for (int j = 0; j < 4; ++j) {
        float j1 = j1_of(yv[j], l1v[j], gi == gj0 + j, eta, c1d);
        float j2 = j2_of(yv[j], l2v[j], 1.0f - ai * av[j], eta, ebb);
        float yn = acc[i][j];
        n1[j] = fmaf(0.9f, l1v[j], mu * (j1 - yn));
        n2[j] = fmaf(0.9f, l2v[j], mu * (j2 - yn));
        cv[j] = yn;
      }
      *(float4*)(L1 + ro) = *(float4*)(n1);
      *(float4*)(L2 + ro) = *(float4*)(n2);
      *(float4*)(Cb + (size_t)gi * D + gj0) = *(float4*)(cv);
    }
  }
}

// ---------------- cls init with bias ----------------
__global__ __launch_bounds__(256) void cls_init_kernel(const float* __restrict__ fcb,
                                                       float* __restrict__ cls) {
  int e = blockIdx.x * 256 + threadIdx.x;  // 25600 exactly
  cls[e] = fcb[e % 200];
}

// ---------------- gather tril(Y)*sqrtNorm -> feat[b][32896] ----------------
__global__ __launch_bounds__(256) void gather_kernel(const float* __restrict__ Y,
                                                     const float* __restrict__ stats,
                                                     float* __restrict__ feat, int b0) {
  int bl = blockIdx.x;
  int ib = blockIdx.y;  // 8 row-groups of 32
  float s = stats[NB + b0 + bl];
  const float* Yb = Y + ((size_t)bl << 16);
  float* fb = feat + (size_t)bl * 32896;
  for (int i = ib * 32; i < ib * 32 + 32; ++i) {
    int base = i * (i + 1) / 2;
    for (int j = threadIdx.x; j <= i; j += 256)
      fb[base + j] = Yb[(i << 8) + j] * s;
  }
}

// ---------------- fc: cls += feat @ fcw^T (split-K, atomic) ----------------
__global__ __launch_bounds__(256) void fc_kernel(const float* __restrict__ feat,
                                                 const float* __restrict__ fcw,
                                                 float* __restrict__ cls,
                                                 int b0, int Bg) {
  const int KTOT = 32896;
  int kspl = blockIdx.x;   // 32 splits of 1028
  int oblk = blockIdx.y;   // 25 groups of 8 outputs
  int bgrp = blockIdx.z;   // groups of 32 batches
  int kbeg = kspl * 1028, kend = kbeg + 1028;
  __shared__ __align__(16) float fs[32][132];
  __shared__ __align__(16) float wsh[8][132];
  int t = threadIdx.x;
  int bb = t >> 3, oo = t & 7;
  float acc = 0.f;
  for (int k0 = kbeg; k0 < kend; k0 += 128) {
#pragma unroll
    for (int l = 0; l < 16; ++l) {
      int li = t + l * 256;
      int kk = li & 127, rb = li >> 7;
      int bl = bgrp * 32 + rb;
      int kg = k0 + kk;
      float v = 0.f;
      if (bl < Bg && kg < kend) v = feat[(size_t)bl * KTOT + kg];
      fs[rb][kk] = v;
    }
#pragma unroll
    for (int l = 0; l < 4; ++l) {
      int li = t + l * 256;
      int kk = li & 127, ro = li >> 7;
      int kg = k0 + kk;
      wsh[ro][kk] = (kg < kend) ? fcw[(size_t)(oblk * 8 + ro) * KTOT + kg] : 0.f;
    }
    __syncthreads();
#pragma unroll
    for (int kk = 0; kk < 128; kk += 4) {
      float4 f4 = *(const float4*)&fs[bb][kk];
      float4 w4 = *(const float4*)&wsh[oo][kk];
      acc = fmaf(f4.x, w4.x, acc);
      acc = fmaf(f4.y, w4.y, acc);
      acc = fmaf(f4.z, w4.z, acc);
      acc = fmaf(f4.w, w4.w, acc);
    }
    __syncthreads();
  }
  int bl = bgrp * 32 + bb;
  if (bl < Bg) atomicAdd(&cls[(b0 + bl) * 200 + oblk * 8 + oo], acc);
}

extern "C" void kernel_launch(void* const* d_in, const int* in_sizes, int n_in,
                              void* d_out, int out_size, void* d_ws, size_t ws_size,
                              hipStream_t stream) {
  const float* pro = (const float*)d_in[0];
  const float* w1  = (const float*)d_in[1];
  const float* w2  = (const float*)d_in[2];
  const float* fcw = (const float*)d_in[3];
  const float* fcb = (const float*)d_in[4];

  float* cls  = (float*)d_out;
  float* Aout = cls + 25600;
  float* satt = Aout + (size_t)NB * D * D;

  float* g     = (float*)d_ws;
  float* att   = g + NB * D;
  float* stats = att + NB * D;

  // choose batch-chunk size: fixed (g,att,stats) + feat[Bg][32896] + 6 pool bufs
  int Bg = NB;
  while (Bg > 1) {
    size_t need = (size_t)(2 * NB * D + 512) * 4 + (size_t)Bg * 32896 * 4 +
                  6ull * (size_t)Bg * D * D * 4;
    if (need <= ws_size) break;
    Bg >>= 1;
  }
  float* feat = stats + 512;
  float* pool = feat + (size_t)Bg * 32896;

  mean_kernel<<<dim3(64, NB), 256, 0, stream>>>(pro, g);
  att_kernel<<<dim3(NB), 256, 0, stream>>>(g, w1, w2, att, satt);
  gram_kernel<<<dim3(4, NB), 256, 0, stream>>>(pro, g, Aout);
  trace_kernel<<<dim3(NB), 64, 0, stream>>>(Aout, stats);
  cls_init_kernel<<<dim3(100), 256, 0, stream>>>(fcb, cls);

  for (int b0 = 0; b0 < NB; b0 += Bg) {
    float* S[6];
    for (int i = 0; i < 6; ++i) S[i] = pool + (size_t)i * Bg * D * D;
    float *Y = S[0], *L1 = S[1], *L2 = S[2], *Zc = S[3], *fA = S[4], *fB = S[5];
    int ge = Bg * 64;
    dim3 bgrid(16, Bg);

    init_kernel<<<dim3(ge), 256, 0, stream>>>(Aout, stats, b0, Y, Zc, L1, L2);

    double mu = 0.5;
    for (int it = 0; it < 7; ++it) {
      float eta  = (float)(1.0 / mu);
      float c1d  = (float)(1.0 - 1e-3 / mu);
      float ebb  = (float)(1e-3 / mu);
      float eta3 = (float)(1.0 / (2.0 * mu));
      float muf  = (float)mu;

      float* P = fA;
      pre_kernel<<<dim3(ge), 256, 0, stream>>>(Y, L1, L2, att, b0, P, eta, c1d, ebb, eta3);

      if (it == 0) {
        // Ynew = Yp @ ZY0 (ZY0 in Zc from init) + fused L-update, in-place over Y
        bmm_kernel<<<bgrid, 256, 0, stream>>>(P, Zc, Y, Y, L1, L2, att, b0,
                                              1.0f, 0.f, 1, muf, eta, c1d, ebb);
        // Z stays = ZY0 (Zc); P dead -> fA still free
      } else {
        float* ZY = fB;
        bmm_kernel<<<bgrid, 256, 0, stream>>>(Zc, P, ZY, nullptr, nullptr, nullptr, att, b0,
                                              -0.5f, 1.5f, 0, 0.f, 0.f, 0.f, 0.f);
        bmm_kernel<<<bgrid, 256, 0, stream>>>(P, ZY, Y, Y, L1, L2, att, b0,
                                              1.0f, 0.f, (it < 6) ? 1 : 0, muf, eta, c1d, ebb);
        if (it < 6) {
          bmm_kernel<<<bgrid, 256, 0, stream>>>(ZY, Zc, P, nullptr, nullptr, nullptr, att, b0,
                                                1.0f, 0.f, 0, 0.f, 0.f, 0.f, 0.f);
          float* oldZ = Zc;
          Zc = P;     // Znew
          fA = ZY;    // dead after Znew matmul
          fB = oldZ;  // dead
        }
      }
      if (it < 6) mu *= 1.05;
    }

    gather_kernel<<<dim3(Bg, 8), 256, 0, stream>>>(Y, stats, feat, b0);
    fc_kernel<<<dim3(32, 25, (Bg + 31) / 32), 256, 0, stream>>>(feat, fcw, cls, b0, Bg);
  }
}

// Round 4
// 1538.689 us; speedup vs baseline: 1.3162x; 1.2424x over previous
//
#include <hip/hip_runtime.h>
#include <math.h>

#define D 256
#define HW 784
#define NB 128

typedef float f32x4 __attribute__((ext_vector_type(4)));
typedef short bf16x8 __attribute__((ext_vector_type(8)));

// split fp32 -> hi (RNE bf16) + lo (trunc bf16 of residual), returned in low 16 bits
__device__ __forceinline__ void splitbf(float x, uint& h, uint& l) {
  uint u = __float_as_uint(x);
  uint r = u + 0x7fffu + ((u >> 16) & 1u);
  h = r >> 16;
  float hf = __uint_as_float(h << 16);
  l = __float_as_uint(x - hf) >> 16;
}

__device__ __forceinline__ void pack8(const float* v, uint* hp, uint* lp) {
#pragma unroll
  for (int p = 0; p < 4; ++p) {
    uint h0, l0, h1, l1;
    splitbf(v[2 * p], h0, l0);
    splitbf(v[2 * p + 1], h1, l1);
    hp[p] = h0 | (h1 << 16);
    lp[p] = l0 | (l1 << 16);
  }
}

// LDS slot addressing (uint units). Page = 1KB per (rf,kc); 64 slots of 16B.
__device__ __forceinline__ uint slotU(int rf, int kc, int r16, int kg) {
  return ((uint)(rf * 2 + kc) << 8) + ((uint)(((r16 << 2) | kg) ^ (rf & 7)) << 2);
}
__device__ __forceinline__ uint slotG(int rf, int r16, int kg) {
  return ((uint)rf << 8) + ((uint)(((r16 << 2) | kg) ^ (rf & 7)) << 2);
}

// ---------------- mean over spatial ----------------
__global__ __launch_bounds__(256) void mean_kernel(const float* __restrict__ pro,
                                                   float* __restrict__ g) {
  int b = blockIdx.y;
  int c = blockIdx.x * 4 + (threadIdx.x >> 6);
  int lane = threadIdx.x & 63;
  const float4* p4 = (const float4*)(pro + ((size_t)b * D + c) * HW);
  float s = 0.f;
  for (int i = lane; i < 196; i += 64) {
    float4 v = p4[i];
    s += v.x + v.y + v.z + v.w;
  }
#pragma unroll
  for (int o = 32; o > 0; o >>= 1) s += __shfl_down(s, o);
  if (lane == 0) g[b * D + c] = s * (1.0f / (float)HW);
}

// ---------------- att MLP + s_att outer ----------------
__global__ __launch_bounds__(256) void att_kernel(const float* __restrict__ g,
                                                  const float* __restrict__ w1,
                                                  const float* __restrict__ w2,
                                                  float* __restrict__ att,
                                                  float* __restrict__ satt) {
  __shared__ float gs[D];
  __shared__ float hs[16];
  __shared__ float as[D];
  int b = blockIdx.x, t = threadIdx.x;
  gs[t] = g[b * D + t];
  __syncthreads();
  if (t < 16) {
    float s = 0.f;
    for (int c = 0; c < D; ++c) s = fmaf(w1[t * D + c], gs[c], s);
    hs[t] = s;
  }
  __syncthreads();
  float s = 0.f;
#pragma unroll
  for (int k = 0; k < 16; ++k) s = fmaf(w2[t * 16 + k], hs[k], s);
  float a = 1.0f / (1.0f + expf(-s));
  as[t] = a;
  att[b * D + t] = a;
  __syncthreads();
  float* sb = satt + (size_t)b * D * D;
  for (int e = t; e < D * D; e += 256) sb[e] = as[e >> 8] * as[e & 255];
}

// ---------------- covariance A = X@X^T/784 - g g^T  (MFMA split-bf16) ----------------
__global__ __launch_bounds__(256) void gram_mfma(const float* __restrict__ pro,
                                                 const float* __restrict__ g,
                                                 float* __restrict__ Aout) {
  __shared__ uint lds[8192];  // Ah 0, Al 2048, Bh 4096, Bl 6144 (uint units)
  int b = blockIdx.y;
  int bi = blockIdx.x & 1, bj = blockIdx.x >> 1;
  int t = threadIdx.x;
  const float* Xb = pro + (size_t)b * D * HW;
  int lane = t & 63, w = t >> 6, wr = w >> 1, wc = w & 1;
  int r16 = lane & 15, kg = lane >> 4;
  f32x4 acc[4][4] = {};
  int row = t >> 1;
  int kseg = (t & 1) << 4;
  int kg0 = (t & 1) << 1;
  for (int k0 = 0; k0 < 800; k0 += 32) {
#pragma unroll
    for (int side = 0; side < 2; ++side) {
      int grow = (side ? bj : bi) * 128 + row;
      const float* src = Xb + (size_t)grow * HW + k0 + kseg;
      float v[16];
#pragma unroll
      for (int i = 0; i < 16; i += 4) {
        int kk = k0 + kseg + i;
        if (kk + 3 < HW) {
          float4 f = *(const float4*)(src + i);
          v[i] = f.x; v[i + 1] = f.y; v[i + 2] = f.z; v[i + 3] = f.w;
        } else {
#pragma unroll
          for (int jj = 0; jj < 4; ++jj) v[i + jj] = (kk + jj < HW) ? src[i + jj] : 0.0f;
        }
      }
      uint base = side ? 4096u : 0u;
      int rf = row >> 4, rr = row & 15;
#pragma unroll
      for (int hh = 0; hh < 2; ++hh) {
        uint hp[4], lp[4];
        pack8(v + hh * 8, hp, lp);
        uint sx = slotG(rf, rr, kg0 + hh);
        *(uint4*)&lds[base + sx] = make_uint4(hp[0], hp[1], hp[2], hp[3]);
        *(uint4*)&lds[base + 2048 + sx] = make_uint4(lp[0], lp[1], lp[2], lp[3]);
      }
    }
    __syncthreads();
    bf16x8 ah[4], al[4], bh[4], bl[4];
#pragma unroll
    for (int f = 0; f < 4; ++f) {
      uint sa = slotG(wr * 4 + f, r16, kg);
      ah[f] = *(const bf16x8*)&lds[sa];
      al[f] = *(const bf16x8*)&lds[2048 + sa];
      uint sb = slotG(wc * 4 + f, r16, kg);
      bh[f] = *(const bf16x8*)&lds[4096 + sb];
      bl[f] = *(const bf16x8*)&lds[6144 + sb];
    }
#pragma unroll
    for (int m = 0; m < 4; ++m)
#pragma unroll
      for (int n = 0; n < 4; ++n) {
        acc[m][n] = __builtin_amdgcn_mfma_f32_16x16x32_bf16(ah[m], bh[n], acc[m][n], 0, 0, 0);
        acc[m][n] = __builtin_amdgcn_mfma_f32_16x16x32_bf16(ah[m], bl[n], acc[m][n], 0, 0, 0);
        acc[m][n] = __builtin_amdgcn_mfma_f32_16x16x32_bf16(al[m], bh[n], acc[m][n], 0, 0, 0);
      }
    __syncthreads();
  }
  const float inv = 1.0f / (float)HW;
  const float* gb = g + b * D;
  float* Cb = Aout + ((size_t)b << 16);
#pragma unroll
  for (int m = 0; m < 4; ++m)
#pragma unroll
    for (int n = 0; n < 4; ++n)
#pragma unroll
      for (int r = 0; r < 4; ++r) {
        int grow = bi * 128 + wr * 64 + m * 16 + ((lane >> 4) << 2) + r;
        int gcol = bj * 128 + wc * 64 + n * 16 + (lane & 15);
        Cb[(size_t)grow * D + gcol] = fmaf(-gb[grow], gb[gcol], acc[m][n][r] * inv);
      }
}

// ---------------- trace ----------------
__global__ void trace_kernel(const float* __restrict__ A, float* __restrict__ stats) {
  int b = blockIdx.x;
  int l = threadIdx.x;  // 64 threads
  float s = 0.f;
  for (int d = l; d < D; d += 64) s += A[(size_t)b * D * D + d * (D + 1)];
#pragma unroll
  for (int o = 32; o > 0; o >>= 1) s += __shfl_down(s, o);
  if (l == 0) {
    stats[b] = 1.0f / s;       // invNorm
    stats[NB + b] = sqrtf(s);  // sqrtNorm
  }
}

__device__ __forceinline__ float j1_of(float y, float l1, bool diag, float eta, float c1d) {
  float j1 = fmaf(-eta, l1, y);
  return diag ? j1 * c1d : j1;
}
__device__ __forceinline__ float j2_of(float y, float l2, float oma, float eta, float ebb) {
  return fmaf(-eta, l2, y) * (1.0f - ebb * oma);
}

// ---------------- pre: Ypre = 0.5(J1+J2) + eta3(L1+L2) ----------------
__global__ __launch_bounds__(256) void pre_kernel(const float* __restrict__ Y,
                                                  const float* __restrict__ L1,
                                                  const float* __restrict__ L2,
                                                  const float* __restrict__ att, int b0,
                                                  float* __restrict__ Yp,
                                                  float eta, float c1d, float ebb, float eta3) {
  int idx = blockIdx.x * 256 + threadIdx.x;
  int bloc = idx >> 14;
  int m4 = idx & 16383;
  int i = m4 >> 6;
  int j0 = (m4 & 63) << 2;
  size_t o = (size_t)idx << 2;
  float4 y = *(const float4*)(Y + o);
  float4 l1 = *(const float4*)(L1 + o);
  float4 l2 = *(const float4*)(L2 + o);
  float ai = att[(b0 + bloc) * D + i];
  float4 aj = *(const float4*)(att + (b0 + bloc) * D + j0);
  float4 r;
  {
    float j1 = j1_of(y.x, l1.x, i == j0 + 0, eta, c1d);
    float j2 = j2_of(y.x, l2.x, 1.0f - ai * aj.x, eta, ebb);
    r.x = 0.5f * (j1 + j2) + eta3 * (l1.x + l2.x);
  }
  {
    float j1 = j1_of(y.y, l1.y, i == j0 + 1, eta, c1d);
    float j2 = j2_of(y.y, l2.y, 1.0f - ai * aj.y, eta, ebb);
    r.y = 0.5f * (j1 + j2) + eta3 * (l1.y + l2.y);
  }
  {
    float j1 = j1_of(y.z, l1.z, i == j0 + 2, eta, c1d);
    float j2 = j2_of(y.z, l2.z, 1.0f - ai * aj.z, eta, ebb);
    r.z = 0.5f * (j1 + j2) + eta3 * (l1.z + l2.z);
  }
  {
    float j1 = j1_of(y.w, l1.w, i == j0 + 3, eta, c1d);
    float j2 = j2_of(y.w, l2.w, 1.0f - ai * aj.w, eta, ebb);
    r.w = 0.5f * (j1 + j2) + eta3 * (l1.w + l2.w);
  }
  *(float4*)(Yp + o) = r;
}

// ---------------- batched 256^3 MFMA split-bf16 GEMM with fused modes ----------------
// aMode/bMode: 0 = plain matrix; 1 = ZY0 derived from A (1.5I - 0.5*A*invn);
//              2 = Yp0 derived from A (it0 pre).
// epMode: 0 = C = alpha*acc + delta*I; 1 = L-update (Yold = Y buffer); 2 = L-fresh (Yold = A*invn).
__global__ __launch_bounds__(256) void bmm_mfma(
    const float* Am, const float* Bm, float* Cm,
    const float* Ao, const float* Yold, float* L1, float* L2,
    const float* att, const float* stats,
    int b0, int aMode, int bMode, int epMode,
    float alpha, float delta, float mu, float eta, float c1d, float ebb) {
  __shared__ uint lds[16384];  // Ah 0, Al 4096, Bh 8192, Bl 12288 (uint units)
  int b = blockIdx.y, bg = b0 + b;
  int bi = blockIdx.x & 1, bj = blockIdx.x >> 1;
  int t = threadIdx.x;
  float invn = stats[bg];
  const float* Ab = aMode ? (Ao + ((size_t)bg << 16)) : (Am + ((size_t)b << 16));
  const float* Bb = bMode ? (Ao + ((size_t)bg << 16)) : (Bm + ((size_t)b << 16));
  const float* attb = att + bg * D;
  int lane = t & 63, w = t >> 6, wr = w >> 1, wc = w & 1;
  int r16 = lane & 15, kg = lane >> 4;
  f32x4 acc[4][4] = {};
  int arow = t >> 2;        // 0..63
  int kseg = (t & 3) << 4;  // 0,16,32,48
  int kcA = (t & 3) >> 1;
  int kgA = (kseg >> 3) & 3;  // 0,2,0,2
  int cq = (t & 31) << 2;     // 0..124
  int ab = t >> 5;            // 0..7
  for (int k0 = 0; k0 < D; k0 += 64) {
    // ---- stage A-operand ----
#pragma unroll
    for (int half = 0; half < 2; ++half) {
      int r = arow + half * 64;
      int grow = bi * 128 + r;
      const float* src = Ab + (size_t)grow * D + k0 + kseg;
      float v[16];
#pragma unroll
      for (int i = 0; i < 16; i += 4) {
        float4 f = *(const float4*)(src + i);
        v[i] = f.x; v[i + 1] = f.y; v[i + 2] = f.z; v[i + 3] = f.w;
      }
      if (aMode == 1) {
#pragma unroll
        for (int i = 0; i < 16; ++i) {
          int j = k0 + kseg + i;
          v[i] = (grow == j ? 1.5f : 0.0f) - 0.5f * v[i] * invn;
        }
      } else if (aMode == 2) {
        float ai = attb[grow];
#pragma unroll
        for (int i = 0; i < 16; ++i) {
          int j = k0 + kseg + i;
          float y = v[i] * invn;
          float j1 = (grow == j) ? y * c1d : y;
          float j2 = y * (1.0f - ebb * (1.0f - ai * attb[j]));
          v[i] = 0.5f * (j1 + j2);
        }
      }
      int rf = r >> 4, rr = r & 15;
#pragma unroll
      for (int hh = 0; hh < 2; ++hh) {
        uint hp[4], lp[4];
        pack8(v + hh * 8, hp, lp);
        uint sx = slotU(rf, kcA, rr, kgA + hh);
        *(uint4*)&lds[sx] = make_uint4(hp[0], hp[1], hp[2], hp[3]);
        *(uint4*)&lds[4096 + sx] = make_uint4(lp[0], lp[1], lp[2], lp[3]);
      }
    }
    // ---- stage B-operand (transposed into col-major slots) ----
    {
      const float* src = Bb + (size_t)(k0 + ab * 8) * D + bj * 128 + cq;
      float fv[32];
#pragma unroll
      for (int j = 0; j < 8; ++j) {
        float4 f = *(const float4*)(src + j * D);
        fv[j * 4 + 0] = f.x; fv[j * 4 + 1] = f.y; fv[j * 4 + 2] = f.z; fv[j * 4 + 3] = f.w;
      }
      if (bMode == 1) {
#pragma unroll
        for (int j = 0; j < 8; ++j) {
          int irow = k0 + ab * 8 + j;
#pragma unroll
          for (int i2 = 0; i2 < 4; ++i2) {
            int c = bj * 128 + cq + i2;
            fv[j * 4 + i2] = (irow == c ? 1.5f : 0.0f) - 0.5f * fv[j * 4 + i2] * invn;
          }
        }
      } else if (bMode == 2) {
#pragma unroll
        for (int j = 0; j < 8; ++j) {
          int irow = k0 + ab * 8 + j;
          float ai = attb[irow];
#pragma unroll
          for (int i2 = 0; i2 < 4; ++i2) {
            int c = bj * 128 + cq + i2;
            float y = fv[j * 4 + i2] * invn;
            float j1 = (irow == c) ? y * c1d : y;
            float j2 = y * (1.0f - ebb * (1.0f - ai * attb[c]));
            fv[j * 4 + i2] = 0.5f * (j1 + j2);
          }
        }
      }
      int kcB = ab >> 2, kgB = ab & 3;
#pragma unroll
      for (int i2 = 0; i2 < 4; ++i2) {
        int c = cq + i2;
        float vv[8];
#pragma unroll
        for (int j = 0; j < 8; ++j) vv[j] = fv[j * 4 + i2];
        uint hp[4], lp[4];
        pack8(vv, hp, lp);
        uint sx = slotU(c >> 4, kcB, c & 15, kgB);
        *(uint4*)&lds[8192 + sx] = make_uint4(hp[0], hp[1], hp[2], hp[3]);
        *(uint4*)&lds[12288 + sx] = make_uint4(lp[0], lp[1], lp[2], lp[3]);
      }
    }
    __syncthreads();
    // ---- compute ----
#pragma unroll
    for (int kc = 0; kc < 2; ++kc) {
      bf16x8 ah[4], al[4], bh[4], bl[4];
#pragma unroll
      for (int f = 0; f < 4; ++f) {
        uint sa = slotU(wr * 4 + f, kc, r16, kg);
        ah[f] = *(const bf16x8*)&lds[sa];
        al[f] = *(const bf16x8*)&lds[4096 + sa];
        uint sb = slotU(wc * 4 + f, kc, r16, kg);
        bh[f] = *(const bf16x8*)&lds[8192 + sb];
        bl[f] = *(const bf16x8*)&lds[12288 + sb];
      }
#pragma unroll
      for (int m = 0; m < 4; ++m)
#pragma unroll
        for (int n = 0; n < 4; ++n) {
          acc[m][n] = __builtin_amdgcn_mfma_f32_16x16x32_bf16(ah[m], bh[n], acc[m][n], 0, 0, 0);
          acc[m][n] = __builtin_amdgcn_mfma_f32_16x16x32_bf16(ah[m], bl[n], acc[m][n], 0, 0, 0);
          acc[m][n] = __builtin_amdgcn_mfma_f32_16x16x32_bf16(al[m], bh[n], acc[m][n], 0, 0, 0);
        }
    }
    __syncthreads();
  }
  // ---- epilogue ----
  float* Cb = Cm + ((size_t)b << 16);
#pragma unroll
  for (int m = 0; m < 4; ++m)
#pragma unroll
    for (int n = 0; n < 4; ++n)
#pragma unroll
      for (int r = 0; r < 4; ++r) {
        int grow = bi * 128 + wr * 64 + m * 16 + ((lane >> 4) << 2) + r;
        int gcol = bj * 128 + wc * 64 + n * 16 + (lane & 15);
        float yn = acc[m][n][r];
        size_t off = (size_t)grow * D + gcol;
        if (epMode == 0) {
          Cb[off] = alpha * yn + ((grow == gcol) ? delta : 0.0f);
        } else {
          size_t lo = ((size_t)b << 16) + off;
          float y, l1v, l2v;
          if (epMode == 2) {
            y = Ao[((size_t)bg << 16) + off] * invn;
            l1v = 0.0f;
            l2v = 0.0f;
          } else {
            y = Yold[lo];
            l1v = L1[lo];
            l2v = L2[lo];
          }
          float ai = attb[grow], aj = attb[gcol];
          float j1 = fmaf(-eta, l1v, y);
          if (grow == gcol) j1 *= c1d;
          float j2 = fmaf(-eta, l2v, y) * (1.0f - ebb * (1.0f - ai * aj));
          L1[lo] = fmaf(0.9f, l1v, mu * (j1 - yn));
          L2[lo] = fmaf(0.9f, l2v, mu * (j2 - yn));
          Cb[off] = yn;
        }
      }
}

// ---------------- cls init with bias ----------------
__global__ __launch_bounds__(256) void cls_init_kernel(const float* __restrict__ fcb,
                                                       float* __restrict__ cls) {
  int e = blockIdx.x * 256 + threadIdx.x;  // 25600 exactly
  cls[e] = fcb[e % 200];
}

// ---------------- gather tril(Y)*sqrtNorm -> feat[b][32896] ----------------
__global__ __launch_bounds__(256) void gather_kernel(const float* __restrict__ Y,
                                                     const float* __restrict__ stats,
                                                     float* __restrict__ feat, int b0) {
  int bl = blockIdx.x;
  int ib = blockIdx.y;  // 8 row-groups of 32
  float s = stats[NB + b0 + bl];
  const float* Yb = Y + ((size_t)bl << 16);
  float* fb = feat + (size_t)bl * 32896;
  for (int i = ib * 32; i < ib * 32 + 32; ++i) {
    int base = i * (i + 1) / 2;
    for (int j = threadIdx.x; j <= i; j += 256) fb[base + j] = Yb[(i << 8) + j] * s;
  }
}

// ---------------- fc: cls += feat @ fcw^T (split-K, atomic) ----------------
__global__ __launch_bounds__(256) void fc_kernel(const float* __restrict__ feat,
                                                 const float* __restrict__ fcw,
                                                 float* __restrict__ cls,
                                                 int b0, int Bg) {
  const int KTOT = 32896;
  int kspl = blockIdx.x;  // 32 splits of 1028
  int oblk = blockIdx.y;  // 25 groups of 8 outputs
  int bgrp = blockIdx.z;  // groups of 32 batches
  int kbeg = kspl * 1028, kend = kbeg + 1028;
  __shared__ __align__(16) float fs[32][132];
  __shared__ __align__(16) float wsh[8][132];
  int t = threadIdx.x;
  int bb = t >> 3, oo = t & 7;
  float acc = 0.f;
  for (int k0 = kbeg; k0 < kend; k0 += 128) {
#pragma unroll
    for (int l = 0; l < 16; ++l) {
      int li = t + l * 256;
      int kk = li & 127, rb = li >> 7;
      int bl = bgrp * 32 + rb;
      int kg2 = k0 + kk;
      float v = 0.f;
      if (bl < Bg && kg2 < kend) v = feat[(size_t)bl * KTOT + kg2];
      fs[rb][kk] = v;
    }
#pragma unroll
    for (int l = 0; l < 4; ++l) {
      int li = t + l * 256;
      int kk = li & 127, ro = li >> 7;
      int kg2 = k0 + kk;
      wsh[ro][kk] = (kg2 < kend) ? fcw[(size_t)(oblk * 8 + ro) * KTOT + kg2] : 0.f;
    }
    __syncthreads();
#pragma unroll
    for (int kk = 0; kk < 128; kk += 4) {
      float4 f4 = *(const float4*)&fs[bb][kk];
      float4 w4 = *(const float4*)&wsh[oo][kk];
      acc = fmaf(f4.x, w4.x, acc);
      acc = fmaf(f4.y, w4.y, acc);
      acc = fmaf(f4.z, w4.z, acc);
      acc = fmaf(f4.w, w4.w, acc);
    }
    __syncthreads();
  }
  int bl = bgrp * 32 + bb;
  if (bl < Bg) atomicAdd(&cls[(b0 + bl) * 200 + oblk * 8 + oo], acc);
}

extern "C" void kernel_launch(void* const* d_in, const int* in_sizes, int n_in,
                              void* d_out, int out_size, void* d_ws, size_t ws_size,
                              hipStream_t stream) {
  const float* pro = (const float*)d_in[0];
  const float* w1 = (const float*)d_in[1];
  const float* w2 = (const float*)d_in[2];
  const float* fcw = (const float*)d_in[3];
  const float* fcb = (const float*)d_in[4];

  float* cls = (float*)d_out;
  float* Aout = cls + 25600;
  float* satt = Aout + (size_t)NB * D * D;

  float* g = (float*)d_ws;
  float* att = g + NB * D;
  float* stats = att + NB * D;

  int Bg = NB;
  while (Bg > 1) {
    size_t need = (size_t)(2 * NB * D + 512) * 4 + (size_t)Bg * 32896 * 4 +
                  6ull * (size_t)Bg * D * D * 4;
    if (need <= ws_size) break;
    Bg >>= 1;
  }
  float* feat = stats + 512;
  float* pool = feat + (size_t)Bg * 32896;

  mean_kernel<<<dim3(64, NB), 256, 0, stream>>>(pro, g);
  att_kernel<<<dim3(NB), 256, 0, stream>>>(g, w1, w2, att, satt);
  gram_mfma<<<dim3(4, NB), 256, 0, stream>>>(pro, g, Aout);
  trace_kernel<<<dim3(NB), 64, 0, stream>>>(Aout, stats);
  cls_init_kernel<<<dim3(100), 256, 0, stream>>>(fcb, cls);

  for (int b0 = 0; b0 < NB; b0 += Bg) {
    float* S[6];
    for (int i = 0; i < 6; ++i) S[i] = pool + (size_t)i * Bg * D * D;
    float *Y = S[0], *L1 = S[1], *L2 = S[2], *Zc = S[3], *fA = S[4], *fB = S[5];
    int ge = Bg * 64;
    dim3 bgrid(4, Bg);

    double mu = 0.5;
    {  // it0: Ynew = Yp0(A) @ ZY0(A), fused L-fresh epilogue
      float eta = 2.0f, c1d = 1.0f - 2e-3f, ebb = 2e-3f;
      bmm_mfma<<<bgrid, 256, 0, stream>>>(Aout, Aout, Y, Aout, Y, L1, L2, att, stats, b0,
                                          2, 1, 2, 1.0f, 0.0f, 0.5f, eta, c1d, ebb);
    }
    mu *= 1.05;
    for (int it = 1; it < 7; ++it) {
      float eta = (float)(1.0 / mu);
      float c1d = (float)(1.0 - 1e-3 / mu);
      float ebb = (float)(1e-3 / mu);
      float eta3 = (float)(1.0 / (2.0 * mu));
      float muf = (float)mu;

      pre_kernel<<<dim3(ge), 256, 0, stream>>>(Y, L1, L2, att, b0, fA, eta, c1d, ebb, eta3);
      // bmm1: ZY = 1.5I - 0.5 * Z @ Yp  -> fB   (it==1: Z derived from A)
      bmm_mfma<<<bgrid, 256, 0, stream>>>(Zc, fA, fB, Aout, Y, L1, L2, att, stats, b0,
                                          (it == 1) ? 1 : 0, 0, 0, -0.5f, 1.5f,
                                          muf, eta, c1d, ebb);
      // bmm2: Ynew = Yp @ ZY -> Y, fused L-update (it<6) or plain (it==6)
      bmm_mfma<<<bgrid, 256, 0, stream>>>(fA, fB, Y, Aout, Y, L1, L2, att, stats, b0,
                                          0, 0, (it < 6) ? 1 : 0, 1.0f, 0.0f,
                                          muf, eta, c1d, ebb);
      if (it < 6) {
        float* zdst = (it == 1) ? Zc : fA;
        // bmm3: Znew = ZY @ Z -> zdst (it==1: Z derived from A)
        bmm_mfma<<<bgrid, 256, 0, stream>>>(fB, Zc, zdst, Aout, Y, L1, L2, att, stats, b0,
                                            0, (it == 1) ? 1 : 0, 0, 1.0f, 0.0f,
                                            muf, eta, c1d, ebb);
        if (it > 1) { float* tmp = Zc; Zc = fA; fA = tmp; }
        mu *= 1.05;
      }
    }

    gather_kernel<<<dim3(Bg, 8), 256, 0, stream>>>(Y, stats, feat, b0);
    fc_kernel<<<dim3(32, 25, (Bg + 31) / 32), 256, 0, stream>>>(feat, fcw, cls, b0, Bg);
  }
}